// Round 12
// baseline (132.516 us; speedup 1.0000x reference)
//
#include <hip/hip_runtime.h>

#define NCOMP 19
#define NB    4096

typedef float f32x4 __attribute__((ext_vector_type(4)));

// ---- compile-time tables ----
constexpr float S20[21] = {
  0.0f, 0.15643446504023087f, 0.3090169943749474f, 0.45399049973954675f,
  0.5877852522924731f, 0.7071067811865476f, 0.8090169943749475f,
  0.8910065241883679f, 0.9510565162951535f, 0.9876883405951378f, 1.0f,
  0.9876883405951378f, 0.9510565162951535f, 0.8910065241883679f,
  0.8090169943749475f, 0.7071067811865476f, 0.5877852522924731f,
  0.45399049973954675f, 0.3090169943749474f, 0.15643446504023087f, 0.0f};

__host__ __device__ constexpr float sval(int m) {          // sin(m*pi/20)
  return (m <= 20) ? S20[m] : -S20[m - 20];
}
__host__ __device__ constexpr float vconst(int k, int j) { // V[k][j]
  return sval(((k + 1) * (j + 1)) % 40) * 0.31622776601683794f;
}

struct Tabs { float v[NCOMP][NCOMP]; float lam[NCOMP]; };
__host__ __device__ constexpr Tabs make_tabs() {
  Tabs T{};
  for (int k = 0; k < NCOMP; ++k) {
    for (int j = 0; j < NCOMP; ++j) T.v[k][j] = vconst(k, j);
    T.lam[k] = -2.0f * (1.0f - sval((k + 11) % 40));       // -4 sin^2((k+1)pi/40)
  }
  return T;
}
__constant__ Tabs VT = make_tabs();

// ---- DPP wave64 inclusive scan ----
template <int CTRL, int RMASK>
__device__ __forceinline__ float dpp_add(float x) {
  int v = __builtin_amdgcn_update_dpp(0, __float_as_int(x), CTRL, RMASK, 0xf, true);
  return x + __int_as_float(v);
}
__device__ __forceinline__ float wave_iscan(float x) {
  x = dpp_add<0x111, 0xf>(x);
  x = dpp_add<0x112, 0xf>(x);
  x = dpp_add<0x114, 0xf>(x);
  x = dpp_add<0x118, 0xf>(x);
  x = dpp_add<0x142, 0xa>(x);
  x = dpp_add<0x143, 0xc>(x);
  return x;
}

// reference-identical RK4 (setup only)
__device__ __forceinline__ void derivf(const float* __restrict__ y, float a, float bin,
                                       float* __restrict__ k) {
#pragma unroll
  for (int j = 0; j < NCOMP; ++j) {
    float s = -2.0f * y[j];
    if (j > 0) s += y[j - 1];
    if (j < NCOMP - 1) s += y[j + 1];
    k[j] = a * s;
  }
  k[NCOMP - 1] += bin;
}
__device__ __forceinline__ void rk4f(float* __restrict__ x, float a, float bin) {
  const float h = 0.01f, h2 = 0.005f, h6 = 0.01f / 6.0f;
  float k[NCOMP], y[NCOMP], acc[NCOMP];
  derivf(x, a, bin, k);
#pragma unroll
  for (int j = 0; j < NCOMP; ++j) { acc[j] = k[j]; y[j] = fmaf(h2, k[j], x[j]); }
  derivf(y, a, bin, k);
#pragma unroll
  for (int j = 0; j < NCOMP; ++j) { acc[j] = fmaf(2.0f, k[j], acc[j]); y[j] = fmaf(h2, k[j], x[j]); }
  derivf(y, a, bin, k);
#pragma unroll
  for (int j = 0; j < NCOMP; ++j) { acc[j] = fmaf(2.0f, k[j], acc[j]); y[j] = fmaf(h, k[j], x[j]); }
  derivf(y, a, bin, k);
#pragma unroll
  for (int j = 0; j < NCOMP; ++j) x[j] = fmaf(h6, acc[j] + k[j], x[j]);
}

// in-place Horner stage: u <- x + c * T * u  (scalar carry, T = tridiag(1,-2,1))
__device__ __forceinline__ void stage_ip(float c, float* __restrict__ u,
                                         const float* __restrict__ x) {
  float prev = u[0];
  u[0] = fmaf(c, fmaf(-2.0f, u[0], u[1]), x[0]);
#pragma unroll
  for (int j = 1; j < NCOMP - 1; ++j) {
    float cur = u[j];
    u[j] = fmaf(c, fmaf(-2.0f, cur, prev + u[j + 1]), x[j]);
    prev = cur;
  }
  u[NCOMP - 1] = fmaf(c, fmaf(-2.0f, u[NCOMP - 1], prev), x[NCOMP - 1]);
}

// x <- R4(ha*T) x + iin*d   (== one RK4 step; only x,t arrays live)
__device__ __forceinline__ void step4(float* __restrict__ x, float* __restrict__ t,
                                      float ha, const float4 d, float iin) {
  const float c1 = ha * 0.25f;
  t[0] = fmaf(c1, fmaf(-2.0f, x[0], x[1]), x[0]);
#pragma unroll
  for (int j = 1; j < NCOMP - 1; ++j)
    t[j] = fmaf(c1, fmaf(-2.0f, x[j], x[j - 1] + x[j + 1]), x[j]);
  t[NCOMP - 1] = fmaf(c1, fmaf(-2.0f, x[NCOMP - 1], x[NCOMP - 2]), x[NCOMP - 1]);
  stage_ip(ha * (1.0f / 3.0f), t, x);
  stage_ip(ha * 0.5f, t, x);
  x[0] = fmaf(ha, fmaf(-2.0f, t[0], t[1]), x[0]);
#pragma unroll
  for (int j = 1; j < NCOMP - 1; ++j)
    x[j] = fmaf(ha, fmaf(-2.0f, t[j], t[j - 1] + t[j + 1]), x[j]);
  x[NCOMP - 1] = fmaf(ha, fmaf(-2.0f, t[NCOMP - 1], t[NCOMP - 2]), x[NCOMP - 1]);
  x[15] = fmaf(iin, d.x, x[15]);
  x[16] = fmaf(iin, d.y, x[16]);
  x[17] = fmaf(iin, d.z, x[17]);
  x[18] = fmaf(iin, d.w, x[18]);
}

// one block (4 waves) = one (batch, system); thread t owns steps 4t..4t+3.
__global__ __launch_bounds__(256, 4) void spm_fused(
    const float* __restrict__ xin, const float* __restrict__ iseq,
    const float* __restrict__ An, const float* __restrict__ Bn,
    const float* __restrict__ Ap, const float* __restrict__ Bp,
    float* __restrict__ out)
{
  __shared__ float xs0[NCOMP];
  __shared__ float4 mcv[NCOMP];                   // (gi, w*gi, log2 g, s0)
  __shared__ __align__(16) float wtot[NCOMP][4];
  __shared__ float4 dls[2];

  const int t = threadIdx.x;
  const int lane = t & 63, wid = t >> 6;
  const int b = blockIdx.x >> 1, sys = blockIdx.x & 1;
  const float alpha = sys ? Ap[1] : An[1];
  const float ha    = 0.01f * alpha;

  // issue input load early
  const float4 iv = *reinterpret_cast<const float4*>(iseq + (size_t)b * 1024 + t * 4);

  if (t < 2) {
    float al  = t ? Ap[1] : An[1];
    float abv = t ? Bp[NCOMP - 1] : Bn[NCOMP - 1];
    float z[NCOMP];
#pragma unroll
    for (int j = 0; j < NCOMP; ++j) z[j] = 0.0f;
    rk4f(z, al, abv);
    dls[t] = make_float4(z[15], z[16], z[17], z[18]);
  }
  if (t < NCOMP) xs0[t] = xin[(size_t)b * (2 * NCOMP) + sys * NCOMP + t];
  __syncthreads();

  if (t < NCOMP) {
    float ab = sys ? Bp[NCOMP - 1] : Bn[NCOMP - 1];
    float z  = ha * VT.lam[t];
    float g  = 1.0f + z * (1.0f + z * (0.5f + z * ((1.0f/6.0f) + z * (1.0f/24.0f))));
    float S  = 1.0f + z * (0.5f + z * ((1.0f/6.0f) + z * (1.0f/24.0f)));
    float gi = 1.0f / g;
    float s0 = 0.0f;
#pragma unroll
    for (int j = 0; j < NCOMP; ++j) s0 = fmaf(VT.v[t][j], xs0[j], s0);
    mcv[t] = make_float4(gi, 0.01f * S * ab * VT.v[t][NCOMP - 1] * gi,
                         __builtin_log2f(g), s0);
  }
  __syncthreads();

  const float4 dvec = dls[sys];
  const float pos = (float)(4 * t);

  // Phase A: per-mode weighted wave-local scan (DPP)
  float Cp[NCOMP];
#pragma unroll
  for (int k = 0; k < NCOMP; ++k) {
    const float4 c = mcv[k];
    float r = iv.x + c.x * (iv.y + c.x * (iv.z + c.x * iv.w));
    float a = __builtin_exp2f(-pos * c.z) * r;
    float v = wave_iscan(a);
    if (lane == 63) wtot[k][wid] = v;
    Cp[k] = v - a;
  }
  __syncthreads();

  // Phase B: cross-quarter offsets, reconstruct physical x0
  float x0[NCOMP];
#pragma unroll
  for (int j = 0; j < NCOMP; ++j) x0[j] = 0.0f;
#pragma unroll
  for (int k = 0; k < NCOMP; ++k) {
    const float4 c = mcv[k];
    float4 q = *reinterpret_cast<const float4*>(&wtot[k][0]);
    float C = Cp[k];
    if (wid > 0) C += q.x;
    if (wid > 1) C += q.y;
    if (wid > 2) C += q.z;
    float s = __builtin_exp2f(pos * c.z) * fmaf(c.y, C, c.w);
#pragma unroll
    for (int j = 0; j < NCOMP; ++j) x0[j] = fmaf(s, vconst(k, j), x0[j]);
  }
  if (t == 0) {
#pragma unroll
    for (int j = 0; j < NCOMP; ++j) x0[j] = xs0[j];
  }

  // 4 steps; b3 eliminated (last step stored from x0 directly)
  float t1[NCOMP];
  float b0[NCOMP], b1[NCOMP], b2[NCOMP];
  step4(x0, t1, ha, dvec, iv.x);
#pragma unroll
  for (int j = 0; j < NCOMP; ++j) b0[j] = x0[j];
  step4(x0, t1, ha, dvec, iv.y);
#pragma unroll
  for (int j = 0; j < NCOMP; ++j) b1[j] = x0[j];
  step4(x0, t1, ha, dvec, iv.z);
#pragma unroll
  for (int j = 0; j < NCOMP; ++j) b2[j] = x0[j];
  step4(x0, t1, ha, dvec, iv.w);

  float* orow = out + ((size_t)b * (2 * NCOMP) + sys * NCOMP) * 1024 + t * 4;
#pragma unroll
  for (int j = 0; j < NCOMP; ++j) {
    f32x4 v = { b0[j], b1[j], b2[j], x0[j] };
    __builtin_nontemporal_store(v, reinterpret_cast<f32x4*>(orow + (size_t)j * 1024));
  }
}

extern "C" void kernel_launch(void* const* d_in, const int* in_sizes, int n_in,
                              void* d_out, int out_size, void* d_ws, size_t ws_size,
                              hipStream_t stream) {
  const float* x    = (const float*)d_in[0];
  const float* iseq = (const float*)d_in[1];
  const float* An   = (const float*)d_in[2];
  const float* Bn   = (const float*)d_in[3];
  const float* Ap   = (const float*)d_in[4];
  const float* Bp   = (const float*)d_in[5];
  float* out = (float*)d_out;

  spm_fused<<<NB * 2, 256, 0, stream>>>(x, iseq, An, Bn, Ap, Bp, out);
}

// Round 13
// 128.229 us; speedup vs baseline: 1.0334x; 1.0334x over previous
//
#include <hip/hip_runtime.h>

#define NCOMP 19
#define NB    4096

typedef float f32x2 __attribute__((ext_vector_type(2)));
typedef float f32x4 __attribute__((ext_vector_type(4)));

// ---- compile-time tables ----
constexpr float S20[21] = {
  0.0f, 0.15643446504023087f, 0.3090169943749474f, 0.45399049973954675f,
  0.5877852522924731f, 0.7071067811865476f, 0.8090169943749475f,
  0.8910065241883679f, 0.9510565162951535f, 0.9876883405951378f, 1.0f,
  0.9876883405951378f, 0.9510565162951535f, 0.8910065241883679f,
  0.8090169943749475f, 0.7071067811865476f, 0.5877852522924731f,
  0.45399049973954675f, 0.3090169943749474f, 0.15643446504023087f, 0.0f};

__host__ __device__ constexpr float sval(int m) {          // sin(m*pi/20)
  return (m <= 20) ? S20[m] : -S20[m - 20];
}
__host__ __device__ constexpr float vconst(int k, int j) { // V[k][j]
  return sval(((k + 1) * (j + 1)) % 40) * 0.31622776601683794f;
}

struct Tabs { float v[NCOMP][NCOMP]; float lam[NCOMP]; };
__host__ __device__ constexpr Tabs make_tabs() {
  Tabs T{};
  for (int k = 0; k < NCOMP; ++k) {
    for (int j = 0; j < NCOMP; ++j) T.v[k][j] = vconst(k, j);
    T.lam[k] = -2.0f * (1.0f - sval((k + 11) % 40));       // -4 sin^2((k+1)pi/40)
  }
  return T;
}
__constant__ Tabs VT = make_tabs();

// ---- DPP wave64 inclusive scan ----
template <int CTRL, int RMASK>
__device__ __forceinline__ float dpp_add(float x) {
  int v = __builtin_amdgcn_update_dpp(0, __float_as_int(x), CTRL, RMASK, 0xf, true);
  return x + __int_as_float(v);
}
__device__ __forceinline__ float wave_iscan(float x) {
  x = dpp_add<0x111, 0xf>(x);
  x = dpp_add<0x112, 0xf>(x);
  x = dpp_add<0x114, 0xf>(x);
  x = dpp_add<0x118, 0xf>(x);
  x = dpp_add<0x142, 0xa>(x);
  x = dpp_add<0x143, 0xc>(x);
  return x;
}

// one block (4 waves) = one (batch, system); thread t owns steps 4t..4t+3.
__global__ __launch_bounds__(256) void spm_fused(
    const float* __restrict__ xin, const float* __restrict__ iseq,
    const float* __restrict__ An, const float* __restrict__ Bn,
    const float* __restrict__ Ap, const float* __restrict__ Bp,
    float* __restrict__ out)
{
  __shared__ float xs0[NCOMP];
  __shared__ float4 mcv[NCOMP];                   // (gi, w*gi, log2 g, s0)
  __shared__ float2 mgw[NCOMP];                   // (g, w)
  __shared__ __align__(16) float wtot[NCOMP][4];

  const int t = threadIdx.x;
  const int lane = t & 63, wid = t >> 6;
  const int b = blockIdx.x >> 1, sys = blockIdx.x & 1;
  const float alpha = sys ? Ap[1] : An[1];
  const float ha    = 0.01f * alpha;

  // issue input load early
  const float4 iv = *reinterpret_cast<const float4*>(iseq + (size_t)b * 1024 + t * 4);

  if (t < NCOMP) xs0[t] = xin[(size_t)b * (2 * NCOMP) + sys * NCOMP + t];
  __syncthreads();

  if (t < NCOMP) {
    float ab = sys ? Bp[NCOMP - 1] : Bn[NCOMP - 1];
    float z  = ha * VT.lam[t];
    float g  = 1.0f + z * (1.0f + z * (0.5f + z * ((1.0f/6.0f) + z * (1.0f/24.0f))));
    float S  = 1.0f + z * (0.5f + z * ((1.0f/6.0f) + z * (1.0f/24.0f)));
    float gi = 1.0f / g;
    float w  = 0.01f * S * ab * VT.v[t][NCOMP - 1];        // modal input weight
    float s0 = 0.0f;
#pragma unroll
    for (int j = 0; j < NCOMP; ++j) s0 = fmaf(VT.v[t][j], xs0[j], s0);
    mcv[t] = make_float4(gi, w * gi, __builtin_log2f(g), s0);
    mgw[t] = make_float2(g, w);
  }
  __syncthreads();

  const float pos = (float)(4 * t);

  // Phase A: per-mode weighted wave-local scan (DPP)
  float Cp[NCOMP];
#pragma unroll
  for (int k = 0; k < NCOMP; ++k) {
    const float4 c = mcv[k];
    float r = iv.x + c.x * (iv.y + c.x * (iv.z + c.x * iv.w));
    float a = __builtin_exp2f(-pos * c.z) * r;
    float v = wave_iscan(a);
    if (lane == 63) wtot[k][wid] = v;
    Cp[k] = v - a;
  }
  __syncthreads();

  // Phase B: modal start state + 4-step modal evolution, packed (t0,t1)/(t2,t3)
  f32x2 s01[NCOMP], s23[NCOMP];
#pragma unroll
  for (int k = 0; k < NCOMP; ++k) {
    const float4 c = mcv[k];
    const float2 gw = mgw[k];
    float4 q = *reinterpret_cast<const float4*>(&wtot[k][0]);
    float C = Cp[k];
    if (wid > 0) C += q.x;
    if (wid > 1) C += q.y;
    if (wid > 2) C += q.z;
    float s  = __builtin_exp2f(pos * c.z) * fmaf(c.y, C, c.w);  // s_k(4t)
    float sA = fmaf(gw.x, s,  gw.y * iv.x);
    float sB = fmaf(gw.x, sA, gw.y * iv.y);
    float sC = fmaf(gw.x, sB, gw.y * iv.z);
    float sD = fmaf(gw.x, sC, gw.y * iv.w);
    s01[k] = (f32x2){sA, sB};
    s23[k] = (f32x2){sC, sD};
  }

  // Emit: parity-folded rows into registers (packed fma), then terminal burst.
  f32x4 ob[NCOMP];
#pragma unroll
  for (int jj = 0; jj < 9; ++jj) {
    f32x2 E01 = {0.f, 0.f}, E23 = {0.f, 0.f};
    f32x2 O01 = {0.f, 0.f}, O23 = {0.f, 0.f};
#pragma unroll
    for (int k = 0; k < NCOMP; k += 2) {          // even modes: symmetric
      const f32x2 vk = { vconst(k, jj), vconst(k, jj) };
      E01 = __builtin_elementwise_fma(s01[k], vk, E01);
      E23 = __builtin_elementwise_fma(s23[k], vk, E23);
    }
#pragma unroll
    for (int k = 1; k < NCOMP; k += 2) {          // odd modes: antisymmetric
      const f32x2 vk = { vconst(k, jj), vconst(k, jj) };
      O01 = __builtin_elementwise_fma(s01[k], vk, O01);
      O23 = __builtin_elementwise_fma(s23[k], vk, O23);
    }
    f32x2 p01 = E01 + O01, p23 = E23 + O23;
    f32x2 m01 = E01 - O01, m23 = E23 - O23;
    ob[jj]      = (f32x4){p01.x, p01.y, p23.x, p23.y};
    ob[18 - jj] = (f32x4){m01.x, m01.y, m23.x, m23.y};
  }
  {   // center row j=9: odd modes vanish
    f32x2 E01 = {0.f, 0.f}, E23 = {0.f, 0.f};
#pragma unroll
    for (int k = 0; k < NCOMP; k += 2) {
      const f32x2 vk = { vconst(k, 9), vconst(k, 9) };
      E01 = __builtin_elementwise_fma(s01[k], vk, E01);
      E23 = __builtin_elementwise_fma(s23[k], vk, E23);
    }
    ob[9] = (f32x4){E01.x, E01.y, E23.x, E23.y};
  }

  float* orow = out + ((size_t)b * (2 * NCOMP) + sys * NCOMP) * 1024 + t * 4;
#pragma unroll
  for (int j = 0; j < NCOMP; ++j)
    __builtin_nontemporal_store(ob[j], reinterpret_cast<f32x4*>(orow + (size_t)j * 1024));
}

extern "C" void kernel_launch(void* const* d_in, const int* in_sizes, int n_in,
                              void* d_out, int out_size, void* d_ws, size_t ws_size,
                              hipStream_t stream) {
  const float* x    = (const float*)d_in[0];
  const float* iseq = (const float*)d_in[1];
  const float* An   = (const float*)d_in[2];
  const float* Bn   = (const float*)d_in[3];
  const float* Ap   = (const float*)d_in[4];
  const float* Bp   = (const float*)d_in[5];
  float* out = (float*)d_out;

  spm_fused<<<NB * 2, 256, 0, stream>>>(x, iseq, An, Bn, Ap, Bp, out);
}